// Round 10
// baseline (162.408 us; speedup 1.0000x reference)
//
#include <hip/hip_runtime.h>
#include <hip/hip_bf16.h>

typedef float f32x4 __attribute__((ext_vector_type(4)));
typedef __bf16 bf16x8 __attribute__((ext_vector_type(8)));

#define N 8192
#define CH 256
#define NJC 4            // j-chunks
#define JCW (N / NJC)    // 2048 j per chunk
#define JT 64            // j per tile
#define NT (JCW / JT)    // 32 tiles per chunk
#define BM 64            // rows per block

// ---- workspace layout (bytes) ----
static constexpr size_t OFF_P1 = 0;
static constexpr size_t OFF_P2 = 32768;
static constexpr size_t OFF_T1 = 65536;
static constexpr size_t OFF_T2 = 66560;
static constexpr size_t OFF_F1 = 67584;
static constexpr size_t OFF_F2 = OFF_F1 + (size_t)N * 4;
static constexpr size_t OFF_XT = 262144;                       // packed B, 4 MB
static constexpr size_t OFF_SP = OFF_XT + (size_t)CH * N * 2;  // 4x8192 f32
static constexpr size_t OFF_PV = OFF_SP + (size_t)NJC * N * 4; // 3x8 MB

// K1a: partial t-vectors over h-slices of 8.
__global__ __launch_bounds__(256) void k1a(
    const float* __restrict__ W, const float* __restrict__ w1,
    const float* __restrict__ w2, float* __restrict__ p1, float* __restrict__ p2)
{
    int b = blockIdx.x, c = threadIdx.x;
    float a1 = 0.f, a2 = 0.f;
#pragma unroll
    for (int hh = 0; hh < 8; ++hh) {
        int h = b * 8 + hh;
        float wv = W[h * CH + c];
        a1 = __builtin_fmaf(w1[h], wv, a1);
        a2 = __builtin_fmaf(w2[h], wv, a2);
    }
    p1[b * CH + c] = a1;
    p2[b * CH + c] = a2;
}

// K1b: fold 32 partials -> t1,t2.
__global__ __launch_bounds__(256) void k1b(
    const float* __restrict__ p1, const float* __restrict__ p2,
    float* __restrict__ t1, float* __restrict__ t2)
{
    int c = threadIdx.x;
    float a1 = 0.f, a2 = 0.f;
#pragma unroll 8
    for (int b = 0; b < 32; ++b) { a1 += p1[b * CH + c]; a2 += p2[b * CH + c]; }
    t1[c] = a1;
    t2[c] = a2;
}

// KTF: fused pack + f1/f2. inlayer [N][CH] f32 -> xtp fragment-packed bf16 and
// per-row dots f1,f2.
__global__ __launch_bounds__(256) void ktf(
    const float* __restrict__ x, const float* __restrict__ t1,
    const float* __restrict__ t2, const float* __restrict__ b1,
    const float* __restrict__ b2, unsigned short* __restrict__ xtp,
    float* __restrict__ f1, float* __restrict__ f2)
{
    __shared__ unsigned short tile[32][264];     // +8 pad
    int js32 = blockIdx.x;
    int jb = js32 * 32;
    int t = threadIdx.x;
    int lane = t & 63;
    int wv = t >> 6;
    const float4* t1v = (const float4*)t1;
    const float4* t2v = (const float4*)t2;
    float4 ta = t1v[lane], tb = t2v[lane];
    float bb1 = b1[0], bb2 = b2[0];
#pragma unroll
    for (int it = 0; it < 8; ++it) {
        int jr = it * 4 + wv;
        float4 v = *(const float4*)(x + (size_t)(jb + jr) * CH + lane * 4);
        __hip_bfloat16 h0 = __float2bfloat16(v.x);
        __hip_bfloat16 h1 = __float2bfloat16(v.y);
        __hip_bfloat16 h2 = __float2bfloat16(v.z);
        __hip_bfloat16 h3 = __float2bfloat16(v.w);
        tile[jr][lane * 4 + 0] = *(unsigned short*)&h0;
        tile[jr][lane * 4 + 1] = *(unsigned short*)&h1;
        tile[jr][lane * 4 + 2] = *(unsigned short*)&h2;
        tile[jr][lane * 4 + 3] = *(unsigned short*)&h3;
        float d1 = v.x * ta.x + v.y * ta.y + v.z * ta.z + v.w * ta.w;
        float d2 = v.x * tb.x + v.y * tb.y + v.z * tb.z + v.w * tb.w;
#pragma unroll
        for (int off = 32; off; off >>= 1) {
            d1 += __shfl_down(d1, off);
            d2 += __shfl_down(d2, off);
        }
        if (lane == 0) { f1[jb + jr] = d1 + bb1; f2[jb + jr] = d2 + bb2; }
    }
    __syncthreads();
    int r = lane & 15, q = lane >> 4;
#pragma unroll
    for (int pass = 0; pass < 4; ++pass) {
        int ct = pass * 4 + wv;
        unsigned short vs[8];
#pragma unroll
        for (int e = 0; e < 8; ++e) vs[e] = tile[q * 8 + e][ct * 16 + r];
        size_t u = ((size_t)ct * 256 + js32) * 64 + lane;
        *(ulonglong2*)(xtp + u * 8) = *(ulonglong2*)vs;
    }
}

// Raw barrier: LDS visibility only; global loads stay in flight per-wave.
#define BAR() { asm volatile("s_waitcnt lgkmcnt(0)" ::: "memory"); \
                __builtin_amdgcn_s_barrier(); }

// K34 v10: P/C wave specialization + 2 blocks/CU + T5 setprio.
// 512 threads = 8 waves. Waves 0-3: consumers (4 ct's each; MFMA + B loads).
// Waves 4-7: producers (adj load depth-2 + exp + P LDS write).
// BM=64 rows x 2048-j chunk (NJC=4), JT=64, NT=32, grid 512 (2 blocks/CU).
// P double-buffered LDS, XOR-swizzled unit = row*8 + (slot ^ (row&7)).
__global__ __launch_bounds__(512, 4) void k34_fused(
    const int* __restrict__ adj, const float* __restrict__ f1,
    const float* __restrict__ f2, const unsigned short* __restrict__ xtp,
    float* __restrict__ pv0, float* __restrict__ pvx, float* __restrict__ s_part)
{
    __shared__ __align__(16) unsigned short P[2][BM * JT];   // 2 x 8 KB
    __shared__ __align__(16) float f2s[JCW];                 // 8 KB

    const int tid = threadIdx.x;
    const int lane = tid & 63;
    const int w = tid >> 6;              // wave 0..7
    const int r = lane & 15, q = lane >> 4;
    const int bid = blockIdx.x;
    const int jc = bid & 3;              // j-chunk
    const int rb = (bid >> 2) * BM;
    const int jbase = jc * JCW;
    const bool cons = (w < 4);

    // ---- producer setup (waves 4-7): ptid 0..255; row = ptid>>2, 16 j's at (ptid&3)*16
    const int ptid = (tid - 256) & 255;
    const int prow = ptid >> 2;          // 0..63
    const int pjo = (ptid & 3) * 16;
    const int* aptr = adj + (size_t)(rb + prow) * N + jbase + pjo;
    const int s0i = (ptid & 3) * 2;
    const int wu0 = prow * 8 + (s0i ^ (prow & 7));
    const int wu1 = prow * 8 + ((s0i + 1) ^ (prow & 7));
    float f1r = 0.f;
    if (!cons) f1r = f1[rb + prow];

    f32x4 acc[4][4];
#pragma unroll
    for (int mt = 0; mt < 4; ++mt)
#pragma unroll
        for (int i = 0; i < 4; ++i) acc[mt][i] = (f32x4){0.f, 0.f, 0.f, 0.f};
    float s_acc = 0.f;

    int4 RA0, RA1, RA2, RA3, RB0, RB1, RB2, RB3;

#define LOAD_A(R0, R1, R2, R3, t)                                   \
    { const int4* p_ = (const int4*)(aptr + (size_t)(t) * JT);      \
      R0 = p_[0]; R1 = p_[1]; R2 = p_[2]; R3 = p_[3]; }
#define EXPW(R0, R1, R2, R3, buf, tt)                               \
    { float4 g0 = *(const float4*)(&f2s[(tt) * JT + pjo]);          \
      float4 g1 = *(const float4*)(&f2s[(tt) * JT + pjo + 4]);      \
      float4 g2 = *(const float4*)(&f2s[(tt) * JT + pjo + 8]);      \
      float4 g3 = *(const float4*)(&f2s[(tt) * JT + pjo + 12]);     \
      int av[16] = {R0.x, R0.y, R0.z, R0.w, R1.x, R1.y, R1.z, R1.w, \
                    R2.x, R2.y, R2.z, R2.w, R3.x, R3.y, R3.z, R3.w};\
      float gv[16] = {g0.x, g0.y, g0.z, g0.w, g1.x, g1.y, g1.z, g1.w,\
                      g2.x, g2.y, g2.z, g2.w, g3.x, g3.y, g3.z, g3.w};\
      bf16x8 pk0, pk1;                                              \
      _Pragma("unroll")                                             \
      for (int e = 0; e < 16; ++e) {                                \
          float t_ = f1r + gv[e];                                   \
          t_ = fmaxf(t_, 0.01f * t_);                               \
          float p_ = (av[e] > 0) ? __expf(t_) : 0.f;                \
          s_acc += p_;                                              \
          if (e < 8) pk0[e] = (__bf16)p_; else pk1[e - 8] = (__bf16)p_; \
      }                                                             \
      *reinterpret_cast<bf16x8*>(&P[buf][(size_t)wu0 * 8]) = pk0;   \
      *reinterpret_cast<bf16x8*>(&P[buf][(size_t)wu1 * 8]) = pk1; }
// consumer: wave w covers cts w*4..w*4+3; tile tt covers js32 = jc*64 + tt*2 + kk
#define MFMA_TILE(tt, buf)                                          \
    { __builtin_amdgcn_s_setprio(1);                                \
      _Pragma("unroll")                                             \
      for (int kk = 0; kk < 2; ++kk) {                              \
          bf16x8 Bv[4];                                             \
          _Pragma("unroll")                                         \
          for (int i = 0; i < 4; ++i) {                             \
              size_t u_ = ((size_t)(w * 4 + i) * 256 + jc * 64 + (tt) * 2 + kk) * 64 + lane; \
              Bv[i] = *(const bf16x8*)(xtp + u_ * 8);               \
          }                                                         \
          _Pragma("unroll")                                         \
          for (int mt = 0; mt < 4; ++mt) {                          \
              int ua = (mt * 16 + r) * 8 + ((kk * 4 + q) ^ (r & 7));\
              bf16x8 A = *(const bf16x8*)(&P[buf][(size_t)ua * 8]); \
              _Pragma("unroll")                                     \
              for (int i = 0; i < 4; ++i)                           \
                  acc[mt][i] = __builtin_amdgcn_mfma_f32_16x16x32_bf16(A, Bv[i], acc[mt][i], 0, 0, 0); \
          }                                                         \
      }                                                             \
      __builtin_amdgcn_s_setprio(0); }

    // prologue: producers start adj stream, everyone stages f2s
    if (!cons) {
        LOAD_A(RA0, RA1, RA2, RA3, 0);
        LOAD_A(RB0, RB1, RB2, RB3, 1);
    }
    *(float4*)(&f2s[tid * 4]) = *(const float4*)(f2 + jbase + tid * 4);
    __syncthreads();                      // f2s staged (full drain once)
    if (!cons) EXPW(RA0, RA1, RA2, RA3, 0, 0);
    BAR();                                // P[0] ready

    for (int t = 0; t < NT; t += 2) {
        if (cons) {
            MFMA_TILE(t, 0);
        } else {
            if (t + 2 < NT) LOAD_A(RA0, RA1, RA2, RA3, t + 2);
            EXPW(RB0, RB1, RB2, RB3, 1, t + 1);
        }
        BAR();
        if (cons) {
            MFMA_TILE(t + 1, 1);
        } else {
            if (t + 3 < NT) LOAD_A(RB0, RB1, RB2, RB3, t + 3);
            if (t + 2 < NT) EXPW(RA0, RA1, RA2, RA3, 0, t + 2);
        }
        BAR();
    }

    if (!cons) {
        // row-sum partial: 4 producer threads per row (consecutive lanes)
        s_acc += __shfl_xor(s_acc, 1);
        s_acc += __shfl_xor(s_acc, 2);
        if ((lane & 3) == 0) s_part[jc * N + rb + prow] = s_acc;
    } else {
        // write PV partial. D layout: col = lane&15, row = (lane>>4)*4 + reg
        float* dst = (jc == 0) ? pv0 : (pvx + (size_t)(jc - 1) * N * CH);
#pragma unroll
        for (int mt = 0; mt < 4; ++mt)
#pragma unroll
            for (int i = 0; i < 4; ++i)
#pragma unroll
                for (int reg = 0; reg < 4; ++reg) {
                    int row = rb + mt * 16 + q * 4 + reg;
                    int col = (w * 4 + i) * 16 + r;
                    dst[(size_t)row * CH + col] = acc[mt][i][reg];
                }
    }
#undef LOAD_A
#undef EXPW
#undef MFMA_TILE
}

// K5: out[i][c] = (sum_k pv_k) * inv(sum_k s_k). pv0 lives in d_out.
__global__ __launch_bounds__(256) void k5_reduce(
    const float* __restrict__ pvx, const float* __restrict__ s_part,
    float* __restrict__ out)
{
    int g = blockIdx.x * 256 + threadIdx.x;      // float4 index
    int row = g >> 6;
    float s = s_part[row] + s_part[N + row] + s_part[2 * N + row] + s_part[3 * N + row];
    float inv = (s != 0.f) ? 1.0f / s : 0.f;
    float4* out4 = (float4*)out;
    const float4* p1 = (const float4*)pvx;
    const float4* p2 = p1 + (size_t)N * CH / 4;
    const float4* p3 = p2 + (size_t)N * CH / 4;
    float4 v = out4[g];
    float4 a = p1[g], b = p2[g], c = p3[g];
    v.x = (v.x + a.x + b.x + c.x) * inv;
    v.y = (v.y + a.y + b.y + c.y) * inv;
    v.z = (v.z + a.z + b.z + c.z) * inv;
    v.w = (v.w + a.w + b.w + c.w) * inv;
    out4[g] = v;
}

extern "C" void kernel_launch(void* const* d_in, const int* in_sizes, int n_in,
                              void* d_out, int out_size, void* d_ws, size_t ws_size,
                              hipStream_t stream)
{
    const float* inlayer = (const float*)d_in[0];
    const int*   adj     = (const int*)d_in[1];
    const float* W       = (const float*)d_in[2];
    const float* w1      = (const float*)d_in[3];
    const float* b1      = (const float*)d_in[4];
    const float* w2      = (const float*)d_in[5];
    const float* b2      = (const float*)d_in[6];
    float* out = (float*)d_out;

    char* ws = (char*)d_ws;
    float* p1 = (float*)(ws + OFF_P1);
    float* p2 = (float*)(ws + OFF_P2);
    float* t1 = (float*)(ws + OFF_T1);
    float* t2 = (float*)(ws + OFF_T2);
    float* f1 = (float*)(ws + OFF_F1);
    float* f2 = (float*)(ws + OFF_F2);
    unsigned short* xtp = (unsigned short*)(ws + OFF_XT);
    float* s_part = (float*)(ws + OFF_SP);
    float* pvx = (float*)(ws + OFF_PV);

    k1a<<<dim3(32), dim3(256), 0, stream>>>(W, w1, w2, p1, p2);
    k1b<<<dim3(1), dim3(256), 0, stream>>>(p1, p2, t1, t2);
    ktf<<<dim3(N / 32), dim3(256), 0, stream>>>(
        inlayer, t1, t2, b1, b2, xtp, f1, f2);
    k34_fused<<<dim3((N / BM) * NJC), dim3(512), 0, stream>>>(
        adj, f1, f2, xtp, out, pvx, s_part);
    k5_reduce<<<dim3(N * CH / 4 / 256), dim3(256), 0, stream>>>(pvx, s_part, out);
}